// Round 1
// baseline (631.786 us; speedup 1.0000x reference)
//
#include <hip/hip_runtime.h>

typedef unsigned short u16;
typedef unsigned int u32;
typedef __bf16 bf16x8 __attribute__((ext_vector_type(8)));
typedef float f32x4 __attribute__((ext_vector_type(4)));

#define MFMA(a,b,c) __builtin_amdgcn_mfma_f32_16x16x32_bf16((a),(b),(c),0,0,0)

#define BB 4
#define NN 4096
#define DD 1024
#define HH 16
#define HDIM 64
#define RR 256
#define NBH 64

__device__ __forceinline__ float bf2f(u16 h){
  union { u32 u; float f; } c; c.u = ((u32)h) << 16; return c.f;
}
__device__ __forceinline__ u16 f2bf(float f){
  union { float f; u32 u; } c; c.f = f;
  u32 u = c.u;
  return (u16)((u + 0x7FFFu + ((u >> 16) & 1u)) >> 16);
}
__device__ __forceinline__ f32x4 zero4(){ f32x4 v = {0.f,0.f,0.f,0.f}; return v; }

// ---------------- prep kernels ----------------

__global__ void split_cast_kernel(const float* __restrict__ src,
                                  u16* __restrict__ hi, u16* __restrict__ lo, int n)
{
  int i = blockIdx.x * blockDim.x + threadIdx.x;
  int stride = gridDim.x * blockDim.x;
  for (; i < n; i += stride) {
    float v = src[i];
    u16 h = f2bf(v);
    hi[i] = h;
    lo[i] = f2bf(v - bf2f(h));
  }
}

// src: R x C row-major f32 -> dhi: C x R bf16 (transposed); dlo for src cols < lo_cols
__global__ void transpose_split_kernel(const float* __restrict__ src, int R, int C,
                                       u16* __restrict__ dhi, u16* __restrict__ dlo, int lo_cols)
{
  __shared__ float T[32][33];
  const int c0 = blockIdx.x * 32, r0 = blockIdx.y * 32;
  const int t = threadIdx.x;
  #pragma unroll
  for (int i = 0; i < 4; ++i) {
    int r = t >> 3, c = (t & 7) + i * 8;
    T[r][c] = src[(size_t)(r0 + r) * C + c0 + c];
  }
  __syncthreads();
  #pragma unroll
  for (int i = 0; i < 4; ++i) {
    int r = t >> 3, c = (t & 7) + i * 8;
    float v = T[c][r];
    size_t o = (size_t)(c0 + r) * R + r0 + c;
    u16 h = f2bf(v);
    dhi[o] = h;
    if (c0 + r < lo_cols) dlo[o] = f2bf(v - bf2f(h));
  }
}

// ---------------- GEMM (A row-major, B^T row-major, 128x128 tile) ----------------
// MODE 0: qk scatter (hi/lo split outputs), MODE 1: v scatter, MODE 2: f32 out + bias
template<int NPROD, int MODE>
__launch_bounds__(256)
__global__ void gemm_kernel(const u16* __restrict__ Ahi, const u16* __restrict__ Alo,
                            const u16* __restrict__ Bhi, const u16* __restrict__ Blo,
                            int K,
                            u16* __restrict__ o0, u16* __restrict__ o1,
                            u16* __restrict__ o2, u16* __restrict__ o3,
                            float* __restrict__ fout, const float* __restrict__ bias)
{
  __shared__ __align__(16) u16 Ah[128*40];
  __shared__ __align__(16) u16 Bh[128*40];
  __shared__ __align__(16) u16 Al[NPROD==3 ? 128*40 : 8];
  __shared__ __align__(16) u16 Bl[NPROD==3 ? 128*40 : 8];
  const int t = threadIdx.x;
  const int w = t >> 6, l = t & 63;
  const int m0 = blockIdx.x * 128, n0 = blockIdx.y * 128;
  const int wm = (w & 1) * 64, wn = (w >> 1) * 64;
  const int lr = l & 15, lk = (l >> 4) * 8, l4 = (l >> 4) * 4;
  f32x4 acc[4][4];
  #pragma unroll
  for (int i = 0; i < 4; ++i)
    #pragma unroll
    for (int j = 0; j < 4; ++j) acc[i][j] = zero4();

  for (int k0 = 0; k0 < K; k0 += 32) {
    __syncthreads();
    #pragma unroll
    for (int it = 0; it < 2; ++it) {
      int chunk = t + it * 256;
      int row = chunk >> 2, c8 = (chunk & 3) * 8;
      size_t ga = (size_t)(m0 + row) * K + k0 + c8;
      size_t gb = (size_t)(n0 + row) * K + k0 + c8;
      *(uint4*)&Ah[row*40 + c8] = *(const uint4*)&Ahi[ga];
      *(uint4*)&Bh[row*40 + c8] = *(const uint4*)&Bhi[gb];
      if (NPROD == 3) {
        *(uint4*)&Al[row*40 + c8] = *(const uint4*)&Alo[ga];
        *(uint4*)&Bl[row*40 + c8] = *(const uint4*)&Blo[gb];
      }
    }
    __syncthreads();
    bf16x8 ah[4], bh[4], al[4], bl[4];
    #pragma unroll
    for (int f = 0; f < 4; ++f) {
      ah[f] = *(const bf16x8*)&Ah[(wm + f*16 + lr)*40 + lk];
      bh[f] = *(const bf16x8*)&Bh[(wn + f*16 + lr)*40 + lk];
      if (NPROD == 3) {
        al[f] = *(const bf16x8*)&Al[(wm + f*16 + lr)*40 + lk];
        bl[f] = *(const bf16x8*)&Bl[(wn + f*16 + lr)*40 + lk];
      }
    }
    #pragma unroll
    for (int fm = 0; fm < 4; ++fm)
      #pragma unroll
      for (int fn = 0; fn < 4; ++fn) {
        if (NPROD == 3) {
          acc[fm][fn] = MFMA(al[fm], bh[fn], acc[fm][fn]);
          acc[fm][fn] = MFMA(ah[fm], bl[fn], acc[fm][fn]);
        }
        acc[fm][fn] = MFMA(ah[fm], bh[fn], acc[fm][fn]);
      }
  }

  #pragma unroll
  for (int fm = 0; fm < 4; ++fm)
    #pragma unroll
    for (int fn = 0; fn < 4; ++fn)
      #pragma unroll
      for (int j = 0; j < 4; ++j) {
        int gm = m0 + wm + fm*16 + l4 + j;
        int gc = n0 + wn + fn*16 + lr;
        float v = acc[fm][fn][j];
        if (MODE == 2) {
          fout[(size_t)gm * 1024 + gc] = v + bias[gc];
        } else {
          int hh = (gc >> 6) & 15, hd = gc & 63;
          int b = gm >> 12, tok = gm & 4095;
          size_t idx = ((size_t)(b * HH + hh) * NN + tok) * HDIM + hd;
          if (MODE == 0) {
            u16 hi = f2bf(v), lo = f2bf(v - bf2f(hi));
            if ((gc >> 10) == 0) { o0[idx] = hi; o1[idx] = lo; }
            else                 { o2[idx] = hi; o3[idx] = lo; }
          } else {
            o0[idx] = f2bf(v);
          }
        }
      }
}

// ---------------- K2a: k features + kv_ext accumulation ----------------
// grid (bh=64, split=4), 256 threads. kv_ext = Kf^T @ [V | 1 | 0..] (N=80), K-chunks of 32 rows.
__launch_bounds__(256)
__global__ void k2a_kernel(const u16* __restrict__ khi, const u16* __restrict__ klo,
                           const u16* __restrict__ vb,
                           const u16* __restrict__ phi, const u16* __restrict__ plo,
                           float* __restrict__ kvpart)
{
  __shared__ __align__(16) u16 Kh[32*72];
  __shared__ __align__(16) u16 Kl[32*72];
  __shared__ __align__(16) u16 Kft[256*40];
  __shared__ __align__(16) u16 Vt[80*40];
  __shared__ float xnorm[32];
  const int bh = blockIdx.x, sp = blockIdx.y;
  const int t = threadIdx.x, w = t >> 6, l = t & 63;
  const int lr = l & 15, lk = (l >> 4) * 8, l4 = (l >> 4) * 4;
  const size_t base = (size_t)bh * NN * HDIM;
  f32x4 kvacc[4][5];
  #pragma unroll
  for (int i = 0; i < 4; ++i)
    #pragma unroll
    for (int j = 0; j < 5; ++j) kvacc[i][j] = zero4();

  for (int tile = 0; tile < 32; ++tile) {
    const int nb = sp * 1024 + tile * 32;
    __syncthreads();  // protect LDS from overwrite while prev iter still reading
    {
      int row = t >> 3, c8 = (t & 7) * 8;
      size_t g = base + (size_t)(nb + row) * HDIM + c8;
      *(uint4*)&Kh[row*72 + c8] = *(const uint4*)&khi[g];
      *(uint4*)&Kl[row*72 + c8] = *(const uint4*)&klo[g];
      uint4 vv = *(const uint4*)&vb[g];
      const u16* pv = (const u16*)&vv;
      #pragma unroll
      for (int j = 0; j < 8; ++j) Vt[(c8 + j)*40 + row] = pv[j];
      if (t < 32) {
        Vt[64*40 + t] = 0x3F80u;  // ones column -> k_sum
        #pragma unroll
        for (int d = 65; d < 80; ++d) Vt[d*40 + t] = 0;
      }
    }
    __syncthreads();
    if (t < 32) {
      float s = 0.f;
      for (int d = 0; d < 64; ++d) {
        float q = bf2f(Kh[t*72 + d]) + bf2f(Kl[t*72 + d]);
        s += q * q;
      }
      xnorm[t] = 0.5f * s;
    }
    // feature GEMM: M=32 rows, wave w owns r-cols [64w, 64w+64)
    f32x4 facc[2][4];
    #pragma unroll
    for (int i = 0; i < 2; ++i)
      #pragma unroll
      for (int j = 0; j < 4; ++j) facc[i][j] = zero4();
    #pragma unroll
    for (int ks = 0; ks < 2; ++ks) {
      bf16x8 ah[2], al[2];
      #pragma unroll
      for (int fm = 0; fm < 2; ++fm) {
        ah[fm] = *(const bf16x8*)&Kh[(fm*16 + lr)*72 + ks*32 + lk];
        al[fm] = *(const bf16x8*)&Kl[(fm*16 + lr)*72 + ks*32 + lk];
      }
      #pragma unroll
      for (int fn = 0; fn < 4; ++fn) {
        int r = w*64 + fn*16 + lr;
        bf16x8 pbh = *(const bf16x8*)&phi[r*HDIM + ks*32 + lk];
        bf16x8 pbl = *(const bf16x8*)&plo[r*HDIM + ks*32 + lk];
        #pragma unroll
        for (int fm = 0; fm < 2; ++fm) {
          facc[fm][fn] = MFMA(al[fm], pbh, facc[fm][fn]);
          facc[fm][fn] = MFMA(ah[fm], pbl, facc[fm][fn]);
          facc[fm][fn] = MFMA(ah[fm], pbh, facc[fm][fn]);
        }
      }
    }
    __syncthreads();  // xnorm visible
    #pragma unroll
    for (int fm = 0; fm < 2; ++fm)
      #pragma unroll
      for (int fn = 0; fn < 4; ++fn)
        #pragma unroll
        for (int j = 0; j < 4; ++j) {
          int row = fm*16 + l4 + j;          // n local
          int r = w*64 + fn*16 + lr;
          float e = expf(facc[fm][fn][j] - xnorm[row]) * 0.0625f + 1e-6f;
          Kft[r*40 + row] = f2bf(e);
        }
    __syncthreads();
    // kv accumulate: wave w owns r-rows [64w, 64w+64), K=32 (this tile)
    {
      bf16x8 bv[5];
      #pragma unroll
      for (int fn = 0; fn < 5; ++fn)
        bv[fn] = *(const bf16x8*)&Vt[(fn*16 + lr)*40 + lk];
      #pragma unroll
      for (int fr = 0; fr < 4; ++fr) {
        bf16x8 a = *(const bf16x8*)&Kft[(w*64 + fr*16 + lr)*40 + lk];
        #pragma unroll
        for (int fn = 0; fn < 5; ++fn) kvacc[fr][fn] = MFMA(a, bv[fn], kvacc[fr][fn]);
      }
    }
  }
  // kvpart[bh][sp][d][r]
  #pragma unroll
  for (int fr = 0; fr < 4; ++fr)
    #pragma unroll
    for (int fn = 0; fn < 5; ++fn)
      #pragma unroll
      for (int j = 0; j < 4; ++j) {
        int r = w*64 + fr*16 + l4 + j;
        int d = fn*16 + lr;
        kvpart[(((size_t)bh*4 + sp)*80 + d)*256 + r] = kvacc[fr][fn][j];
      }
}

__global__ void kv_reduce_kernel(const float* __restrict__ kvpart, u16* __restrict__ kvt)
{
  int i = blockIdx.x * 256 + threadIdx.x;
  if (i >= NBH * 80 * 256) return;
  int bh = i / (80 * 256), rem = i - bh * (80 * 256);
  float s = 0.f;
  #pragma unroll
  for (int sp = 0; sp < 4; ++sp)
    s += kvpart[((size_t)bh*4 + sp)*80*256 + rem];
  kvt[i] = f2bf(s);  // kvt[bh][d][r], d<64: kv^T; d==64: k_sum
}

// ---------------- K2b: q features + PV + normalize ----------------
// grid (bh=64, tile=128), 128 threads (2 waves), 32 q-rows per block.
__launch_bounds__(128)
__global__ void k2b_kernel(const u16* __restrict__ qhi, const u16* __restrict__ qlo,
                           const u16* __restrict__ kvt,
                           const u16* __restrict__ phi, const u16* __restrict__ plo,
                           u16* __restrict__ attn)
{
  __shared__ __align__(16) u16 Qh[32*72];
  __shared__ __align__(16) u16 Ql[32*72];
  __shared__ __align__(16) u16 Qf[32*264];
  __shared__ float xnorm[32];
  __shared__ float denom[32];
  const int bh = blockIdx.x, b = bh >> 4, h = bh & 15;
  const int n0 = blockIdx.y * 32;
  const int t = threadIdx.x, w = t >> 6, l = t & 63;
  const int lr = l & 15, lk = (l >> 4) * 8, l4 = (l >> 4) * 4;
  const size_t base = (size_t)bh * NN * HDIM;

  #pragma unroll
  for (int it = 0; it < 2; ++it) {
    int chunk = t + it * 128;
    int row = chunk >> 3, c8 = (chunk & 7) * 8;
    size_t g = base + (size_t)(n0 + row) * HDIM + c8;
    *(uint4*)&Qh[row*72 + c8] = *(const uint4*)&qhi[g];
    *(uint4*)&Ql[row*72 + c8] = *(const uint4*)&qlo[g];
  }
  __syncthreads();
  if (t < 32) {
    float s = 0.f;
    for (int d = 0; d < 64; ++d) {
      float q = bf2f(Qh[t*72 + d]) + bf2f(Ql[t*72 + d]);
      s += q * q;
    }
    xnorm[t] = 0.5f * s;
  }
  // feature GEMM: wave w owns r-cols [128w, 128w+128)
  f32x4 facc[2][8];
  #pragma unroll
  for (int i = 0; i < 2; ++i)
    #pragma unroll
    for (int j = 0; j < 8; ++j) facc[i][j] = zero4();
  #pragma unroll
  for (int ks = 0; ks < 2; ++ks) {
    bf16x8 ah[2], al[2];
    #pragma unroll
    for (int fm = 0; fm < 2; ++fm) {
      ah[fm] = *(const bf16x8*)&Qh[(fm*16 + lr)*72 + ks*32 + lk];
      al[fm] = *(const bf16x8*)&Ql[(fm*16 + lr)*72 + ks*32 + lk];
    }
    #pragma unroll
    for (int fn = 0; fn < 8; ++fn) {
      int r = w*128 + fn*16 + lr;
      bf16x8 pbh = *(const bf16x8*)&phi[r*HDIM + ks*32 + lk];
      bf16x8 pbl = *(const bf16x8*)&plo[r*HDIM + ks*32 + lk];
      #pragma unroll
      for (int fm = 0; fm < 2; ++fm) {
        facc[fm][fn] = MFMA(al[fm], pbh, facc[fm][fn]);
        facc[fm][fn] = MFMA(ah[fm], pbl, facc[fm][fn]);
        facc[fm][fn] = MFMA(ah[fm], pbh, facc[fm][fn]);
      }
    }
  }
  __syncthreads();
  #pragma unroll
  for (int fm = 0; fm < 2; ++fm)
    #pragma unroll
    for (int fn = 0; fn < 8; ++fn)
      #pragma unroll
      for (int j = 0; j < 4; ++j) {
        int row = fm*16 + l4 + j;
        int r = w*128 + fn*16 + lr;
        float e = expf(facc[fm][fn][j] - xnorm[row]) * 0.0625f + 1e-6f;
        Qf[row*264 + r] = f2bf(e);
      }
  __syncthreads();
  // PV: out_ext(32x80) = Qf(32x256) @ kv_ext(256x80); wave w owns rows [16w,16w+16)
  f32x4 oacc[5];
  #pragma unroll
  for (int j = 0; j < 5; ++j) oacc[j] = zero4();
  #pragma unroll
  for (int ks = 0; ks < 8; ++ks) {
    bf16x8 a = *(const bf16x8*)&Qf[(w*16 + lr)*264 + ks*32 + lk];
    #pragma unroll
    for (int fn = 0; fn < 5; ++fn) {
      int d = fn*16 + lr;
      bf16x8 bv = *(const bf16x8*)&kvt[((size_t)bh*80 + d)*256 + ks*32 + lk];
      oacc[fn] = MFMA(a, bv, oacc[fn]);
    }
  }
  if (lr == 0) {
    #pragma unroll
    for (int j = 0; j < 4; ++j) denom[w*16 + l4 + j] = oacc[4][j];
  }
  __syncthreads();
  #pragma unroll
  for (int fn = 0; fn < 4; ++fn)
    #pragma unroll
    for (int j = 0; j < 4; ++j) {
      int row = w*16 + l4 + j;
      int d = fn*16 + lr;
      float v = oacc[fn][j] / (denom[row] + 1e-6f);
      attn[((size_t)b * NN + n0 + row) * DD + h * HDIM + d] = f2bf(v);
    }
}

// ---------------- host ----------------

extern "C" void kernel_launch(void* const* d_in, const int* in_sizes, int n_in,
                              void* d_out, int out_size, void* d_ws, size_t ws_size,
                              hipStream_t stream)
{
  const float* x      = (const float*)d_in[0];
  const float* w_qkv  = (const float*)d_in[1];
  const float* w_proj = (const float*)d_in[2];
  const float* b_proj = (const float*)d_in[3];
  const float* proj   = (const float*)d_in[4];
  float* out = (float*)d_out;

  char* p = (char*)d_ws;
  auto alloc = [&](size_t nbytes) {
    char* r = p; p += (nbytes + 255) & ~(size_t)255; return r;
  };
  const size_t NE = (size_t)16777216;  // B*N*D elements
  u16* xhi  = (u16*)alloc(NE * 2);
  u16* xlo  = (u16*)alloc(NE * 2);
  u16* wth  = (u16*)alloc((size_t)3145728 * 2);
  u16* wtl  = (u16*)alloc((size_t)2097152 * 2);
  u16* wpt  = (u16*)alloc((size_t)1048576 * 2);
  u16* phi  = (u16*)alloc((size_t)16384 * 2);
  u16* plo  = (u16*)alloc((size_t)16384 * 2);
  u16* qhi  = (u16*)alloc(NE * 2);
  u16* qlo  = (u16*)alloc(NE * 2);
  u16* khi  = (u16*)alloc(NE * 2);
  u16* klo  = (u16*)alloc(NE * 2);
  u16* vbuf = (u16*)alloc(NE * 2);
  u16* kvt  = (u16*)alloc((size_t)NBH * 80 * 256 * 2);
  // aliases over dead regions (xhi/xlo are dead after GEMM1; kvpart dead before attn writes)
  float* kvpart = (float*)xlo;        // 21 MB <= 32 MB
  u16*   attn   = xhi;                // 32 MB

  split_cast_kernel<<<2048, 256, 0, stream>>>(x, xhi, xlo, (int)NE);
  split_cast_kernel<<<64, 256, 0, stream>>>(proj, phi, plo, 16384);
  transpose_split_kernel<<<dim3(96, 32), 256, 0, stream>>>(w_qkv, 1024, 3072, wth, wtl, 2048);
  transpose_split_kernel<<<dim3(32, 32), 256, 0, stream>>>(w_proj, 1024, 1024, wpt, wpt, 0);

  // qkv: q,k columns with 3-product split; v columns single product
  gemm_kernel<3, 0><<<dim3(128, 16), 256, 0, stream>>>(
      xhi, xlo, wth, wtl, 1024, qhi, qlo, khi, klo, nullptr, nullptr);
  gemm_kernel<1, 1><<<dim3(128, 8), 256, 0, stream>>>(
      xhi, nullptr, wth + (size_t)2048 * 1024, nullptr, 1024,
      vbuf, nullptr, nullptr, nullptr, nullptr, nullptr);

  k2a_kernel<<<dim3(64, 4), 256, 0, stream>>>(khi, klo, vbuf, phi, plo, kvpart);
  kv_reduce_kernel<<<dim3(5120), 256, 0, stream>>>(kvpart, kvt);
  k2b_kernel<<<dim3(64, 128), 128, 0, stream>>>(qhi, qlo, kvt, phi, plo, attn);

  gemm_kernel<1, 2><<<dim3(128, 8), 256, 0, stream>>>(
      attn, nullptr, wpt, nullptr, 1024,
      nullptr, nullptr, nullptr, nullptr, out, b_proj);
}

// Round 2
// 560.238 us; speedup vs baseline: 1.1277x; 1.1277x over previous
//
#include <hip/hip_runtime.h>

typedef unsigned short u16;
typedef unsigned int u32;
typedef __bf16 bf16x8 __attribute__((ext_vector_type(8)));
typedef float f32x4 __attribute__((ext_vector_type(4)));

#define MFMA(a,b,c) __builtin_amdgcn_mfma_f32_16x16x32_bf16((a),(b),(c),0,0,0)

#define BB 4
#define NN 4096
#define DD 1024
#define HH 16
#define HDIM 64
#define RR 256
#define NBH 64

__device__ __forceinline__ float bf2f(u16 h){
  union { u32 u; float f; } c; c.u = ((u32)h) << 16; return c.f;
}
__device__ __forceinline__ u16 f2bf(float f){
  union { float f; u32 u; } c; c.f = f;
  u32 u = c.u;
  return (u16)((u + 0x7FFFu + ((u >> 16) & 1u)) >> 16);
}
__device__ __forceinline__ f32x4 zero4(){ f32x4 v = {0.f,0.f,0.f,0.f}; return v; }

// async global->LDS, 16B per lane; LDS dest must be wave-uniform base + lane*16
__device__ __forceinline__ void gload16(const void* g, void* l) {
  __builtin_amdgcn_global_load_lds(
      (const __attribute__((address_space(1))) void*)g,
      (__attribute__((address_space(3))) void*)l, 16, 0, 0);
}

// ---------------- prep kernels ----------------

__global__ void split_cast_kernel(const float4* __restrict__ src,
                                  ushort4* __restrict__ hi, ushort4* __restrict__ lo, int n4)
{
  int i = blockIdx.x * blockDim.x + threadIdx.x;
  int stride = gridDim.x * blockDim.x;
  for (; i < n4; i += stride) {
    float4 v = src[i];
    ushort4 h, l4;
    h.x = f2bf(v.x); l4.x = f2bf(v.x - bf2f(h.x));
    h.y = f2bf(v.y); l4.y = f2bf(v.y - bf2f(h.y));
    h.z = f2bf(v.z); l4.z = f2bf(v.z - bf2f(h.z));
    h.w = f2bf(v.w); l4.w = f2bf(v.w - bf2f(h.w));
    hi[i] = h;
    lo[i] = l4;
  }
}

// src: R x C row-major f32 -> dhi: C x R bf16 (transposed); dlo for src cols < lo_cols
__global__ void transpose_split_kernel(const float* __restrict__ src, int R, int C,
                                       u16* __restrict__ dhi, u16* __restrict__ dlo, int lo_cols)
{
  __shared__ float T[32][33];
  const int c0 = blockIdx.x * 32, r0 = blockIdx.y * 32;
  const int t = threadIdx.x;
  #pragma unroll
  for (int i = 0; i < 4; ++i) {
    int r = t >> 3, c = (t & 7) + i * 8;
    T[r][c] = src[(size_t)(r0 + r) * C + c0 + c];
  }
  __syncthreads();
  #pragma unroll
  for (int i = 0; i < 4; ++i) {
    int r = t >> 3, c = (t & 7) + i * 8;
    float v = T[c][r];
    size_t o = (size_t)(c0 + r) * R + r0 + c;
    u16 h = f2bf(v);
    dhi[o] = h;
    if (c0 + r < lo_cols) dlo[o] = f2bf(v - bf2f(h));
  }
}

// ---------------- GEMM (A row-major, B^T row-major, 128x128 tile, gload_lds) ----------------
// NPROD 2: acc += (Ahi+Alo)·Bhi (split-A). NPROD 1: acc += Ahi·Bhi.
// MODE 0: qk scatter (hi/lo split outputs), MODE 1: v scatter, MODE 2: f32 out + bias
template<int NPROD, int MODE>
__launch_bounds__(256)
__global__ void gemm_kernel(const u16* __restrict__ Ahi, const u16* __restrict__ Alo,
                            const u16* __restrict__ Bhi,
                            int K,
                            u16* __restrict__ o0, u16* __restrict__ o1,
                            u16* __restrict__ o2, u16* __restrict__ o3,
                            float* __restrict__ fout, const float* __restrict__ bias)
{
  // linear [128][32] — required by global_load_lds (wave-uniform dest + lane*16)
  __shared__ __align__(16) u16 Ah[128*32];
  __shared__ __align__(16) u16 Bh[128*32];
  __shared__ __align__(16) u16 Al[NPROD==2 ? 128*32 : 8];
  const int t = threadIdx.x;
  const int w = t >> 6, l = t & 63;
  const int m0 = blockIdx.x * 128, n0 = blockIdx.y * 128;
  const int wm = (w & 1) * 64, wn = (w >> 1) * 64;
  const int lr = l & 15, lk = (l >> 4) * 8, l4 = (l >> 4) * 4;
  // staging coords: chunk = w*2+it covers rows [chunk*16, chunk*16+16)
  const int sr = l >> 2;            // row within chunk
  const int sc = (l & 3) * 8;       // col (elems)
  f32x4 acc[4][4];
  #pragma unroll
  for (int i = 0; i < 4; ++i)
    #pragma unroll
    for (int j = 0; j < 4; ++j) acc[i][j] = zero4();

  for (int k0 = 0; k0 < K; k0 += 32) {
    __syncthreads();   // prev iter done reading LDS
    #pragma unroll
    for (int it = 0; it < 2; ++it) {
      const int chunk = w * 2 + it;
      const int row = chunk * 16 + sr;
      const size_t ga = (size_t)(m0 + row) * K + k0 + sc;
      const size_t gb = (size_t)(n0 + row) * K + k0 + sc;
      u16* ldst = nullptr;  // dest base per chunk; lane*16B implicit
      gload16(&Ahi[ga], &Ah[chunk * 512 + l * 8]);
      gload16(&Bhi[gb], &Bh[chunk * 512 + l * 8]);
      if (NPROD == 2) gload16(&Alo[ga], &Al[chunk * 512 + l * 8]);
      (void)ldst;
    }
    __syncthreads();   // drains vmcnt: loads landed
    bf16x8 ah[4], bh[4], al[4];
    #pragma unroll
    for (int f = 0; f < 4; ++f) {
      ah[f] = *(const bf16x8*)&Ah[(wm + f*16 + lr)*32 + lk];
      bh[f] = *(const bf16x8*)&Bh[(wn + f*16 + lr)*32 + lk];
      if (NPROD == 2) al[f] = *(const bf16x8*)&Al[(wm + f*16 + lr)*32 + lk];
    }
    #pragma unroll
    for (int fm = 0; fm < 4; ++fm)
      #pragma unroll
      for (int fn = 0; fn < 4; ++fn) {
        if (NPROD == 2) acc[fm][fn] = MFMA(al[fm], bh[fn], acc[fm][fn]);
        acc[fm][fn] = MFMA(ah[fm], bh[fn], acc[fm][fn]);
      }
  }

  #pragma unroll
  for (int fm = 0; fm < 4; ++fm)
    #pragma unroll
    for (int fn = 0; fn < 4; ++fn)
      #pragma unroll
      for (int j = 0; j < 4; ++j) {
        int gm = m0 + wm + fm*16 + l4 + j;
        int gc = n0 + wn + fn*16 + lr;
        float v = acc[fm][fn][j];
        if (MODE == 2) {
          fout[(size_t)gm * 1024 + gc] = v + bias[gc];
        } else {
          int hh = (gc >> 6) & 15, hd = gc & 63;
          int b = gm >> 12, tok = gm & 4095;
          size_t idx = ((size_t)(b * HH + hh) * NN + tok) * HDIM + hd;
          if (MODE == 0) {
            u16 hi = f2bf(v), lo = f2bf(v - bf2f(hi));
            if ((gc >> 10) == 0) { o0[idx] = hi; o1[idx] = lo; }
            else                 { o2[idx] = hi; o3[idx] = lo; }
          } else {
            o0[idx] = f2bf(v);
          }
        }
      }
}

// ---------------- K2a: k features + kv_ext accumulation ----------------
// grid (bh=64, split=4), 256 threads. kv_ext = Kf^T @ [V | 1 | 0..] (N=80), K-chunks of 32 rows.
__launch_bounds__(256)
__global__ void k2a_kernel(const u16* __restrict__ khi, const u16* __restrict__ klo,
                           const u16* __restrict__ vb,
                           const u16* __restrict__ phi, const u16* __restrict__ plo,
                           float* __restrict__ kvpart)
{
  __shared__ __align__(16) u16 Kh[32*72];
  __shared__ __align__(16) u16 Kl[32*72];
  __shared__ __align__(16) u16 Kft[256*40];
  __shared__ __align__(16) u16 Vt[80*40];
  __shared__ float xnorm[32];
  const int bh = blockIdx.x, sp = blockIdx.y;
  const int t = threadIdx.x, w = t >> 6, l = t & 63;
  const int lr = l & 15, lk = (l >> 4) * 8, l4 = (l >> 4) * 4;
  const size_t base = (size_t)bh * NN * HDIM;
  f32x4 kvacc[4][5];
  #pragma unroll
  for (int i = 0; i < 4; ++i)
    #pragma unroll
    for (int j = 0; j < 5; ++j) kvacc[i][j] = zero4();

  for (int tile = 0; tile < 32; ++tile) {
    const int nb = sp * 1024 + tile * 32;
    __syncthreads();  // protect LDS from overwrite while prev iter still reading
    {
      int row = t >> 3, c8 = (t & 7) * 8;
      size_t g = base + (size_t)(nb + row) * HDIM + c8;
      *(uint4*)&Kh[row*72 + c8] = *(const uint4*)&khi[g];
      *(uint4*)&Kl[row*72 + c8] = *(const uint4*)&klo[g];
      uint4 vv = *(const uint4*)&vb[g];
      const u16* pv = (const u16*)&vv;
      #pragma unroll
      for (int j = 0; j < 8; ++j) Vt[(c8 + j)*40 + row] = pv[j];
      if (t < 32) {
        Vt[64*40 + t] = 0x3F80u;  // ones column -> k_sum
        #pragma unroll
        for (int d = 65; d < 80; ++d) Vt[d*40 + t] = 0;
      }
    }
    __syncthreads();
    if (t < 32) {
      float s = 0.f;
      for (int d = 0; d < 64; ++d) {
        float q = bf2f(Kh[t*72 + d]) + bf2f(Kl[t*72 + d]);
        s += q * q;
      }
      xnorm[t] = 0.5f * s;
    }
    // feature GEMM: M=32 rows, wave w owns r-cols [64w, 64w+64)
    f32x4 facc[2][4];
    #pragma unroll
    for (int i = 0; i < 2; ++i)
      #pragma unroll
      for (int j = 0; j < 4; ++j) facc[i][j] = zero4();
    #pragma unroll
    for (int ks = 0; ks < 2; ++ks) {
      bf16x8 ah[2], al[2];
      #pragma unroll
      for (int fm = 0; fm < 2; ++fm) {
        ah[fm] = *(const bf16x8*)&Kh[(fm*16 + lr)*72 + ks*32 + lk];
        al[fm] = *(const bf16x8*)&Kl[(fm*16 + lr)*72 + ks*32 + lk];
      }
      #pragma unroll
      for (int fn = 0; fn < 4; ++fn) {
        int r = w*64 + fn*16 + lr;
        bf16x8 pbh = *(const bf16x8*)&phi[r*HDIM + ks*32 + lk];
        bf16x8 pbl = *(const bf16x8*)&plo[r*HDIM + ks*32 + lk];
        #pragma unroll
        for (int fm = 0; fm < 2; ++fm) {
          facc[fm][fn] = MFMA(al[fm], pbh, facc[fm][fn]);
          facc[fm][fn] = MFMA(ah[fm], pbl, facc[fm][fn]);
          facc[fm][fn] = MFMA(ah[fm], pbh, facc[fm][fn]);
        }
      }
    }
    __syncthreads();  // xnorm visible
    #pragma unroll
    for (int fm = 0; fm < 2; ++fm)
      #pragma unroll
      for (int fn = 0; fn < 4; ++fn)
        #pragma unroll
        for (int j = 0; j < 4; ++j) {
          int row = fm*16 + l4 + j;          // n local
          int r = w*64 + fn*16 + lr;
          float e = expf(facc[fm][fn][j] - xnorm[row]) * 0.0625f + 1e-6f;
          Kft[r*40 + row] = f2bf(e);
        }
    __syncthreads();
    // kv accumulate: wave w owns r-rows [64w, 64w+64), K=32 (this tile)
    {
      bf16x8 bv[5];
      #pragma unroll
      for (int fn = 0; fn < 5; ++fn)
        bv[fn] = *(const bf16x8*)&Vt[(fn*16 + lr)*40 + lk];
      #pragma unroll
      for (int fr = 0; fr < 4; ++fr) {
        bf16x8 a = *(const bf16x8*)&Kft[(w*64 + fr*16 + lr)*40 + lk];
        #pragma unroll
        for (int fn = 0; fn < 5; ++fn) kvacc[fr][fn] = MFMA(a, bv[fn], kvacc[fr][fn]);
      }
    }
  }
  // kvpart[bh][sp][d][r]
  #pragma unroll
  for (int fr = 0; fr < 4; ++fr)
    #pragma unroll
    for (int fn = 0; fn < 5; ++fn)
      #pragma unroll
      for (int j = 0; j < 4; ++j) {
        int r = w*64 + fr*16 + l4 + j;
        int d = fn*16 + lr;
        kvpart[(((size_t)bh*4 + sp)*80 + d)*256 + r] = kvacc[fr][fn][j];
      }
}

__global__ void kv_reduce_kernel(const float* __restrict__ kvpart, u16* __restrict__ kvt)
{
  int i = blockIdx.x * 256 + threadIdx.x;
  if (i >= NBH * 80 * 256) return;
  int bh = i / (80 * 256), rem = i - bh * (80 * 256);
  float s = 0.f;
  #pragma unroll
  for (int sp = 0; sp < 4; ++sp)
    s += kvpart[((size_t)bh*4 + sp)*80*256 + rem];
  kvt[i] = f2bf(s);  // kvt[bh][d][r], d<64: kv^T; d==64: k_sum
}

// ---------------- K2b: q features + PV + normalize ----------------
// grid (bh=64, tile=128), 128 threads (2 waves), 32 q-rows per block.
__launch_bounds__(128)
__global__ void k2b_kernel(const u16* __restrict__ qhi, const u16* __restrict__ qlo,
                           const u16* __restrict__ kvt,
                           const u16* __restrict__ phi, const u16* __restrict__ plo,
                           u16* __restrict__ attn)
{
  __shared__ __align__(16) u16 Qh[32*72];
  __shared__ __align__(16) u16 Ql[32*72];
  __shared__ __align__(16) u16 Qf[32*264];
  __shared__ float xnorm[32];
  __shared__ float denom[32];
  const int bh = blockIdx.x, b = bh >> 4, h = bh & 15;
  const int n0 = blockIdx.y * 32;
  const int t = threadIdx.x, w = t >> 6, l = t & 63;
  const int lr = l & 15, lk = (l >> 4) * 8, l4 = (l >> 4) * 4;
  const size_t base = (size_t)bh * NN * HDIM;

  #pragma unroll
  for (int it = 0; it < 2; ++it) {
    int chunk = t + it * 128;
    int row = chunk >> 3, c8 = (chunk & 7) * 8;
    size_t g = base + (size_t)(n0 + row) * HDIM + c8;
    *(uint4*)&Qh[row*72 + c8] = *(const uint4*)&qhi[g];
    *(uint4*)&Ql[row*72 + c8] = *(const uint4*)&qlo[g];
  }
  __syncthreads();
  if (t < 32) {
    float s = 0.f;
    for (int d = 0; d < 64; ++d) {
      float q = bf2f(Qh[t*72 + d]) + bf2f(Ql[t*72 + d]);
      s += q * q;
    }
    xnorm[t] = 0.5f * s;
  }
  // feature GEMM: wave w owns r-cols [128w, 128w+128)
  f32x4 facc[2][8];
  #pragma unroll
  for (int i = 0; i < 2; ++i)
    #pragma unroll
    for (int j = 0; j < 8; ++j) facc[i][j] = zero4();
  #pragma unroll
  for (int ks = 0; ks < 2; ++ks) {
    bf16x8 ah[2], al[2];
    #pragma unroll
    for (int fm = 0; fm < 2; ++fm) {
      ah[fm] = *(const bf16x8*)&Qh[(fm*16 + lr)*72 + ks*32 + lk];
      al[fm] = *(const bf16x8*)&Ql[(fm*16 + lr)*72 + ks*32 + lk];
    }
    #pragma unroll
    for (int fn = 0; fn < 8; ++fn) {
      int r = w*128 + fn*16 + lr;
      bf16x8 pbh = *(const bf16x8*)&phi[r*HDIM + ks*32 + lk];
      bf16x8 pbl = *(const bf16x8*)&plo[r*HDIM + ks*32 + lk];
      #pragma unroll
      for (int fm = 0; fm < 2; ++fm) {
        facc[fm][fn] = MFMA(al[fm], pbh, facc[fm][fn]);
        facc[fm][fn] = MFMA(ah[fm], pbl, facc[fm][fn]);
        facc[fm][fn] = MFMA(ah[fm], pbh, facc[fm][fn]);
      }
    }
  }
  __syncthreads();
  #pragma unroll
  for (int fm = 0; fm < 2; ++fm)
    #pragma unroll
    for (int fn = 0; fn < 8; ++fn)
      #pragma unroll
      for (int j = 0; j < 4; ++j) {
        int row = fm*16 + l4 + j;
        int r = w*128 + fn*16 + lr;
        float e = expf(facc[fm][fn][j] - xnorm[row]) * 0.0625f + 1e-6f;
        Qf[row*264 + r] = f2bf(e);
      }
  __syncthreads();
  // PV: out_ext(32x80) = Qf(32x256) @ kv_ext(256x80); wave w owns rows [16w,16w+16)
  f32x4 oacc[5];
  #pragma unroll
  for (int j = 0; j < 5; ++j) oacc[j] = zero4();
  #pragma unroll
  for (int ks = 0; ks < 8; ++ks) {
    bf16x8 a = *(const bf16x8*)&Qf[(w*16 + lr)*264 + ks*32 + lk];
    #pragma unroll
    for (int fn = 0; fn < 5; ++fn) {
      int d = fn*16 + lr;
      bf16x8 bv = *(const bf16x8*)&kvt[((size_t)bh*80 + d)*256 + ks*32 + lk];
      oacc[fn] = MFMA(a, bv, oacc[fn]);
    }
  }
  if (lr == 0) {
    #pragma unroll
    for (int j = 0; j < 4; ++j) denom[w*16 + l4 + j] = oacc[4][j];
  }
  __syncthreads();
  #pragma unroll
  for (int fn = 0; fn < 4; ++fn)
    #pragma unroll
    for (int j = 0; j < 4; ++j) {
      int row = w*16 + l4 + j;
      int d = fn*16 + lr;
      float v = oacc[fn][j] / (denom[row] + 1e-6f);
      attn[((size_t)b * NN + n0 + row) * DD + h * HDIM + d] = f2bf(v);
    }
}

// ---------------- host ----------------

extern "C" void kernel_launch(void* const* d_in, const int* in_sizes, int n_in,
                              void* d_out, int out_size, void* d_ws, size_t ws_size,
                              hipStream_t stream)
{
  const float* x      = (const float*)d_in[0];
  const float* w_qkv  = (const float*)d_in[1];
  const float* w_proj = (const float*)d_in[2];
  const float* b_proj = (const float*)d_in[3];
  const float* proj   = (const float*)d_in[4];
  float* out = (float*)d_out;

  char* p = (char*)d_ws;
  auto alloc = [&](size_t nbytes) {
    char* r = p; p += (nbytes + 255) & ~(size_t)255; return r;
  };
  const size_t NE = (size_t)16777216;  // B*N*D elements
  u16* xhi  = (u16*)alloc(NE * 2);
  u16* xlo  = (u16*)alloc(NE * 2);
  u16* wth  = (u16*)alloc((size_t)3145728 * 2);
  u16* wpt  = (u16*)alloc((size_t)1048576 * 2);
  u16* phi  = (u16*)alloc((size_t)16384 * 2);
  u16* plo  = (u16*)alloc((size_t)16384 * 2);
  u16* qhi  = (u16*)alloc(NE * 2);
  u16* qlo  = (u16*)alloc(NE * 2);
  u16* khi  = (u16*)alloc(NE * 2);
  u16* klo  = (u16*)alloc(NE * 2);
  u16* vbuf = (u16*)alloc(NE * 2);
  u16* kvt  = (u16*)alloc((size_t)NBH * 80 * 256 * 2);
  // aliases over dead regions (xlo is dead after gemm<2,0>; xhi dead after gemm<1,1>)
  float* kvpart = (float*)xlo;        // 21 MB <= 32 MB
  u16*   attn   = xhi;                // 32 MB

  split_cast_kernel<<<2048, 256, 0, stream>>>(
      (const float4*)x, (ushort4*)xhi, (ushort4*)xlo, (int)(NE / 4));
  split_cast_kernel<<<16, 256, 0, stream>>>(
      (const float4*)proj, (ushort4*)phi, (ushort4*)plo, 16384 / 4);
  transpose_split_kernel<<<dim3(96, 32), 256, 0, stream>>>(w_qkv, 1024, 3072, wth, nullptr, 0);
  transpose_split_kernel<<<dim3(32, 32), 256, 0, stream>>>(w_proj, 1024, 1024, wpt, nullptr, 0);

  // qkv: q,k columns with 2-product split-A; v columns single product
  gemm_kernel<2, 0><<<dim3(128, 16), 256, 0, stream>>>(
      xhi, xlo, wth, 1024, qhi, qlo, khi, klo, nullptr, nullptr);
  gemm_kernel<1, 1><<<dim3(128, 8), 256, 0, stream>>>(
      xhi, nullptr, wth + (size_t)2048 * 1024, 1024,
      vbuf, nullptr, nullptr, nullptr, nullptr, nullptr);

  k2a_kernel<<<dim3(64, 4), 256, 0, stream>>>(khi, klo, vbuf, phi, plo, kvpart);
  kv_reduce_kernel<<<dim3(5120), 256, 0, stream>>>(kvpart, kvt);
  k2b_kernel<<<dim3(64, 128), 128, 0, stream>>>(qhi, qlo, kvt, phi, plo, attn);

  gemm_kernel<1, 2><<<dim3(128, 8), 256, 0, stream>>>(
      attn, nullptr, wpt, 1024,
      nullptr, nullptr, nullptr, nullptr, out, b_proj);
}

// Round 3
// 440.229 us; speedup vs baseline: 1.4351x; 1.2726x over previous
//
#include <hip/hip_runtime.h>

typedef unsigned short u16;
typedef unsigned int u32;
typedef __bf16 bf16x8 __attribute__((ext_vector_type(8)));
typedef float f32x4 __attribute__((ext_vector_type(4)));

#define MFMA(a,b,c) __builtin_amdgcn_mfma_f32_16x16x32_bf16((a),(b),(c),0,0,0)

#define BB 4
#define NN 4096
#define DD 1024
#define HH 16
#define HDIM 64
#define RR 256
#define NBH 64
#define KSP 8   // k2a splits

__device__ __forceinline__ float bf2f(u16 h){
  union { u32 u; float f; } c; c.u = ((u32)h) << 16; return c.f;
}
__device__ __forceinline__ u16 f2bf(float f){
  union { float f; u32 u; } c; c.f = f;
  u32 u = c.u;
  return (u16)((u + 0x7FFFu + ((u >> 16) & 1u)) >> 16);
}
__device__ __forceinline__ f32x4 zero4(){ f32x4 v = {0.f,0.f,0.f,0.f}; return v; }

// async global->LDS, 16B per lane; LDS dest = wave-uniform base + lane*16
__device__ __forceinline__ void gload16(const void* g, void* l) {
  __builtin_amdgcn_global_load_lds(
      (const __attribute__((address_space(1))) void*)g,
      (__attribute__((address_space(3))) void*)l, 16, 0, 0);
}

// ---------------- prep kernels ----------------

// x (16384 x 1024 f32) -> x2 (16384 x 2048 bf16): row = [hi | lo]
__global__ void split_cast_x2_kernel(const float4* __restrict__ src, u16* __restrict__ x2, int n4)
{
  int i = blockIdx.x * blockDim.x + threadIdx.x;
  int stride = gridDim.x * blockDim.x;
  for (; i < n4; i += stride) {
    float4 v = src[i];
    int m = i >> 8;          // 256 float4 per 1024-row
    int k4 = (i & 255) * 4;
    ushort4 h, lo;
    h.x = f2bf(v.x); lo.x = f2bf(v.x - bf2f(h.x));
    h.y = f2bf(v.y); lo.y = f2bf(v.y - bf2f(h.y));
    h.z = f2bf(v.z); lo.z = f2bf(v.z - bf2f(h.z));
    h.w = f2bf(v.w); lo.w = f2bf(v.w - bf2f(h.w));
    *(ushort4*)&x2[(size_t)m * 2048 + k4] = h;
    *(ushort4*)&x2[(size_t)m * 2048 + 1024 + k4] = lo;
  }
}

// separate hi/lo split (projection)
__global__ void split_cast_kernel(const float4* __restrict__ src,
                                  ushort4* __restrict__ hi, ushort4* __restrict__ lo, int n4)
{
  int i = blockIdx.x * blockDim.x + threadIdx.x;
  int stride = gridDim.x * blockDim.x;
  for (; i < n4; i += stride) {
    float4 v = src[i];
    ushort4 h, l4;
    h.x = f2bf(v.x); l4.x = f2bf(v.x - bf2f(h.x));
    h.y = f2bf(v.y); l4.y = f2bf(v.y - bf2f(h.y));
    h.z = f2bf(v.z); l4.z = f2bf(v.z - bf2f(h.z));
    h.w = f2bf(v.w); l4.w = f2bf(v.w - bf2f(h.w));
    hi[i] = h;
    lo[i] = l4;
  }
}

// w_qkv (1024 x 3072) -> w2qk (2048 x 2048, row n = [w^T_n | w^T_n]) and wv (1024 x 1024 = w^T v-cols)
__global__ void transpose_wqkv_kernel(const float* __restrict__ src,
                                      u16* __restrict__ w2qk, u16* __restrict__ wv)
{
  __shared__ float T[32][33];
  const int c0 = blockIdx.x * 32, r0 = blockIdx.y * 32;
  const int t = threadIdx.x;
  #pragma unroll
  for (int i = 0; i < 4; ++i) {
    int r = t >> 3, c = (t & 7) + i * 8;
    T[r][c] = src[(size_t)(r0 + r) * 3072 + c0 + c];
  }
  __syncthreads();
  #pragma unroll
  for (int i = 0; i < 4; ++i) {
    int r = t >> 3, c = (t & 7) + i * 8;
    float v = T[c][r];
    int orow = c0 + r, ocol = r0 + c;
    u16 h = f2bf(v);
    if (orow < 2048) {
      w2qk[(size_t)orow * 2048 + ocol] = h;
      w2qk[(size_t)orow * 2048 + 1024 + ocol] = h;
    } else {
      wv[(size_t)(orow - 2048) * 1024 + ocol] = h;
    }
  }
}

// w_proj (1024x1024) -> wpt (transposed bf16)
__global__ void transpose_kernel(const float* __restrict__ src, u16* __restrict__ dst)
{
  __shared__ float T[32][33];
  const int c0 = blockIdx.x * 32, r0 = blockIdx.y * 32;
  const int t = threadIdx.x;
  #pragma unroll
  for (int i = 0; i < 4; ++i) {
    int r = t >> 3, c = (t & 7) + i * 8;
    T[r][c] = src[(size_t)(r0 + r) * 1024 + c0 + c];
  }
  __syncthreads();
  #pragma unroll
  for (int i = 0; i < 4; ++i) {
    int r = t >> 3, c = (t & 7) + i * 8;
    dst[(size_t)(c0 + r) * 1024 + r0 + c] = f2bf(T[c][r]);
  }
}

// ---------------- 256x256 pipelined GEMM ----------------
// A: M x K row-major (stride lda), B: N x K row-major (stride ldb) [i.e. B^T].
// 8 waves (2m x 4n), BK=64, 128 KiB LDS dbuf, counted vmcnt(8), T2 swizzle.
// MODE 0: qk hi/lo scatter (N=2048); MODE 1: v scatter; MODE 2: f32 + bias.
template<int MODE>
__launch_bounds__(512, 2)
__global__ void gemm256_kernel(const u16* __restrict__ A, const u16* __restrict__ B,
                               const int K, const int lda, const int ldb,
                               u16* __restrict__ o0, u16* __restrict__ o1,
                               u16* __restrict__ o2, u16* __restrict__ o3,
                               float* __restrict__ fout, const float* __restrict__ bias)
{
  __shared__ __align__(16) u16 lds[2][2][256 * 64];   // [buf][A/B][row*64+col]
  const int t = threadIdx.x;
  const int w = t >> 6, l = t & 63;
  const int m0 = blockIdx.x * 256, n0 = blockIdx.y * 256;
  const int wm = w & 1, wn = w >> 1;           // 2 x 4 wave grid
  const int lr = l & 15, lq = l >> 4;          // frag row / k-quarter
  const int srow = l >> 3;                     // stage: row within 8-row chunk
  const int gs = ((l & 7) ^ srow) * 8;         // pre-swizzled global col (elems)
  const int swz = lr & 7;                      // read-side row xor

  f32x4 acc[8][4];
  #pragma unroll
  for (int m = 0; m < 8; ++m)
    #pragma unroll
    for (int n = 0; n < 4; ++n) acc[m][n] = zero4();

  const int nt = K / 64;

  auto stage = [&](int kt, int bi) {
    #pragma unroll
    for (int i = 0; i < 4; ++i) {
      const int chunk = w * 4 + i;
      const int row = chunk * 8 + srow;
      gload16(&A[(size_t)(m0 + row) * lda + kt * 64 + gs],
              &lds[bi][0][chunk * 512 + l * 8]);
    }
    #pragma unroll
    for (int i = 0; i < 4; ++i) {
      const int chunk = w * 4 + i;
      const int row = chunk * 8 + srow;
      gload16(&B[(size_t)(n0 + row) * ldb + kt * 64 + gs],
              &lds[bi][1][chunk * 512 + l * 8]);
    }
  };

  stage(0, 0);
  stage(1, 1);
  asm volatile("s_waitcnt vmcnt(8)" ::: "memory");   // tile 0 landed (per wave)
  __builtin_amdgcn_s_barrier();
  __builtin_amdgcn_sched_barrier(0);

  for (int kt = 0; kt < nt; ++kt) {
    const int bi = kt & 1;
    const u16* la = &lds[bi][0][0];
    const u16* lb = &lds[bi][1][0];
    bf16x8 a0[8], b0[4], a1[8], b1[4];
    // ks = 0 frags (swizzled read)
    #pragma unroll
    for (int m = 0; m < 8; ++m)
      a0[m] = *(const bf16x8*)&la[(wm*128 + m*16 + lr)*64 + ((lq ^ swz) * 8)];
    #pragma unroll
    for (int n = 0; n < 4; ++n)
      b0[n] = *(const bf16x8*)&lb[(wn*64 + n*16 + lr)*64 + ((lq ^ swz) * 8)];
    __builtin_amdgcn_s_setprio(1);
    #pragma unroll
    for (int m = 0; m < 8; ++m)
      #pragma unroll
      for (int n = 0; n < 4; ++n)
        acc[m][n] = MFMA(a0[m], b0[n], acc[m][n]);
    __builtin_amdgcn_s_setprio(0);
    // ks = 1 frags
    #pragma unroll
    for (int m = 0; m < 8; ++m)
      a1[m] = *(const bf16x8*)&la[(wm*128 + m*16 + lr)*64 + (((4 + lq) ^ swz) * 8)];
    #pragma unroll
    for (int n = 0; n < 4; ++n)
      b1[n] = *(const bf16x8*)&lb[(wn*64 + n*16 + lr)*64 + (((4 + lq) ^ swz) * 8)];
    asm volatile("s_waitcnt lgkmcnt(0)" ::: "memory");  // all our LDS reads in regs
    __builtin_amdgcn_s_barrier();                       // all waves done reading buf bi
    __builtin_amdgcn_sched_barrier(0);
    if (kt + 2 < nt) stage(kt + 2, bi);                 // refill freed buffer
    __builtin_amdgcn_s_setprio(1);
    #pragma unroll
    for (int m = 0; m < 8; ++m)
      #pragma unroll
      for (int n = 0; n < 4; ++n)
        acc[m][n] = MFMA(a1[m], b1[n], acc[m][n]);      // overlaps stage issue
    __builtin_amdgcn_s_setprio(0);
    if (kt + 2 < nt)      { asm volatile("s_waitcnt vmcnt(8)" ::: "memory"); }
    else if (kt + 1 < nt) { asm volatile("s_waitcnt vmcnt(0)" ::: "memory"); }
    __builtin_amdgcn_s_barrier();                       // tile kt+1 ready for all
    __builtin_amdgcn_sched_barrier(0);
  }

  // epilogue
  #pragma unroll
  for (int m = 0; m < 8; ++m)
    #pragma unroll
    for (int n = 0; n < 4; ++n)
      #pragma unroll
      for (int j = 0; j < 4; ++j) {
        int gm = m0 + wm*128 + m*16 + lq*4 + j;
        int gc = n0 + wn*64 + n*16 + lr;
        float v = acc[m][n][j];
        if (MODE == 2) {
          fout[(size_t)gm * 1024 + gc] = v + bias[gc];
        } else {
          int hh = (gc >> 6) & 15, hd = gc & 63;
          int b = gm >> 12, tok = gm & 4095;
          size_t idx = ((size_t)(b * HH + hh) * NN + tok) * HDIM + hd;
          if (MODE == 0) {
            u16 hi = f2bf(v), lo = f2bf(v - bf2f(hi));
            if ((gc >> 10) == 0) { o0[idx] = hi; o1[idx] = lo; }
            else                 { o2[idx] = hi; o3[idx] = lo; }
          } else {
            o0[idx] = f2bf(v);
          }
        }
      }
}

// ---------------- K2a: k features + kv_ext accumulation ----------------
// grid (bh=64, split=KSP), 256 threads. kv_ext = Kf^T @ [V | 1 | 0..] (N=80).
__launch_bounds__(256)
__global__ void k2a_kernel(const u16* __restrict__ khi, const u16* __restrict__ klo,
                           const u16* __restrict__ vb,
                           const u16* __restrict__ phi, const u16* __restrict__ plo,
                           float* __restrict__ kvpart)
{
  __shared__ __align__(16) u16 Kh[32*72];
  __shared__ __align__(16) u16 Kl[32*72];
  __shared__ __align__(16) u16 Kft[256*40];
  __shared__ __align__(16) u16 Vt[80*40];
  __shared__ float xnorm[32];
  const int bh = blockIdx.x, sp = blockIdx.y;
  const int t = threadIdx.x, w = t >> 6, l = t & 63;
  const int lr = l & 15, lk = (l >> 4) * 8, l4 = (l >> 4) * 4;
  const size_t base = (size_t)bh * NN * HDIM;
  f32x4 kvacc[4][5];
  #pragma unroll
  for (int i = 0; i < 4; ++i)
    #pragma unroll
    for (int j = 0; j < 5; ++j) kvacc[i][j] = zero4();

  const int TILES = (NN / KSP) / 32;
  for (int tile = 0; tile < TILES; ++tile) {
    const int nb = sp * (NN / KSP) + tile * 32;
    __syncthreads();  // prev iter done reading LDS
    {
      int row = t >> 3, c8 = (t & 7) * 8;
      size_t g = base + (size_t)(nb + row) * HDIM + c8;
      uint4 khv = *(const uint4*)&khi[g];
      uint4 klv = *(const uint4*)&klo[g];
      *(uint4*)&Kh[row*72 + c8] = khv;
      *(uint4*)&Kl[row*72 + c8] = klv;
      uint4 vv = *(const uint4*)&vb[g];
      const u16* pv = (const u16*)&vv;
      #pragma unroll
      for (int j = 0; j < 8; ++j) Vt[(c8 + j)*40 + row] = pv[j];
      if (t < 32) {
        Vt[64*40 + t] = 0x3F80u;  // ones column -> k_sum
        #pragma unroll
        for (int d = 65; d < 80; ++d) Vt[d*40 + t] = 0;
      }
      // parallel xnorm from staging regs: 8 lanes per row
      const u16* ph = (const u16*)&khv;
      const u16* pl = (const u16*)&klv;
      float s = 0.f;
      #pragma unroll
      for (int j = 0; j < 8; ++j) {
        float qv = bf2f(ph[j]) + bf2f(pl[j]);
        s += qv * qv;
      }
      s += __shfl_xor(s, 1);
      s += __shfl_xor(s, 2);
      s += __shfl_xor(s, 4);
      if ((t & 7) == 0) xnorm[row] = 0.5f * s;
    }
    __syncthreads();
    // feature GEMM: M=32 rows, wave w owns r-cols [64w, 64w+64)
    f32x4 facc[2][4];
    #pragma unroll
    for (int i = 0; i < 2; ++i)
      #pragma unroll
      for (int j = 0; j < 4; ++j) facc[i][j] = zero4();
    #pragma unroll
    for (int ks = 0; ks < 2; ++ks) {
      bf16x8 ah[2], al[2];
      #pragma unroll
      for (int fm = 0; fm < 2; ++fm) {
        ah[fm] = *(const bf16x8*)&Kh[(fm*16 + lr)*72 + ks*32 + lk];
        al[fm] = *(const bf16x8*)&Kl[(fm*16 + lr)*72 + ks*32 + lk];
      }
      #pragma unroll
      for (int fn = 0; fn < 4; ++fn) {
        int r = w*64 + fn*16 + lr;
        bf16x8 pbh = *(const bf16x8*)&phi[r*HDIM + ks*32 + lk];
        bf16x8 pbl = *(const bf16x8*)&plo[r*HDIM + ks*32 + lk];
        #pragma unroll
        for (int fm = 0; fm < 2; ++fm) {
          facc[fm][fn] = MFMA(al[fm], pbh, facc[fm][fn]);
          facc[fm][fn] = MFMA(ah[fm], pbl, facc[fm][fn]);
          facc[fm][fn] = MFMA(ah[fm], pbh, facc[fm][fn]);
        }
      }
    }
    #pragma unroll
    for (int fm = 0; fm < 2; ++fm)
      #pragma unroll
      for (int fn = 0; fn < 4; ++fn)
        #pragma unroll
        for (int j = 0; j < 4; ++j) {
          int row = fm*16 + l4 + j;          // n local
          int r = w*64 + fn*16 + lr;
          float e = __expf(facc[fm][fn][j] - xnorm[row]) * 0.0625f + 1e-6f;
          Kft[r*40 + row] = f2bf(e);
        }
    __syncthreads();
    // kv accumulate: wave w owns r-rows [64w, 64w+64), K=32 (this tile)
    {
      bf16x8 bv[5];
      #pragma unroll
      for (int fn = 0; fn < 5; ++fn)
        bv[fn] = *(const bf16x8*)&Vt[(fn*16 + lr)*40 + lk];
      #pragma unroll
      for (int fr = 0; fr < 4; ++fr) {
        bf16x8 a = *(const bf16x8*)&Kft[(w*64 + fr*16 + lr)*40 + lk];
        #pragma unroll
        for (int fn = 0; fn < 5; ++fn) kvacc[fr][fn] = MFMA(a, bv[fn], kvacc[fr][fn]);
      }
    }
  }
  // kvpart[bh][sp][d][r]
  #pragma unroll
  for (int fr = 0; fr < 4; ++fr)
    #pragma unroll
    for (int fn = 0; fn < 5; ++fn)
      #pragma unroll
      for (int j = 0; j < 4; ++j) {
        int r = w*64 + fr*16 + l4 + j;
        int d = fn*16 + lr;
        kvpart[(((size_t)bh*KSP + sp)*80 + d)*256 + r] = kvacc[fr][fn][j];
      }
}

__global__ void kv_reduce_kernel(const float* __restrict__ kvpart, u16* __restrict__ kvt)
{
  int i = blockIdx.x * 256 + threadIdx.x;
  if (i >= NBH * 80 * 256) return;
  int bh = i / (80 * 256), rem = i - bh * (80 * 256);
  float s = 0.f;
  #pragma unroll
  for (int sp = 0; sp < KSP; ++sp)
    s += kvpart[((size_t)bh*KSP + sp)*80*256 + rem];
  kvt[i] = f2bf(s);  // kvt[bh][d][r], d<64: kv^T; d==64: k_sum
}

// ---------------- K2b: q features + PV + normalize ----------------
// grid (bh=64, tile=128), 128 threads (2 waves), 32 q-rows per block.
__launch_bounds__(128)
__global__ void k2b_kernel(const u16* __restrict__ qhi, const u16* __restrict__ qlo,
                           const u16* __restrict__ kvt,
                           const u16* __restrict__ phi, const u16* __restrict__ plo,
                           u16* __restrict__ attn)
{
  __shared__ __align__(16) u16 Qh[32*72];
  __shared__ __align__(16) u16 Ql[32*72];
  __shared__ __align__(16) u16 Qf[32*264];
  __shared__ float xnorm[32];
  __shared__ float denom[32];
  const int bh = blockIdx.x, b = bh >> 4, h = bh & 15;
  const int n0 = blockIdx.y * 32;
  const int t = threadIdx.x, w = t >> 6, l = t & 63;
  const int lr = l & 15, lk = (l >> 4) * 8, l4 = (l >> 4) * 4;
  const size_t base = (size_t)bh * NN * HDIM;

  #pragma unroll
  for (int it = 0; it < 2; ++it) {
    int chunk = t + it * 128;
    int row = chunk >> 3, c8 = (t & 7) * 8;
    size_t g = base + (size_t)(n0 + row) * HDIM + c8;
    uint4 qhv = *(const uint4*)&qhi[g];
    uint4 qlv = *(const uint4*)&qlo[g];
    *(uint4*)&Qh[row*72 + c8] = qhv;
    *(uint4*)&Ql[row*72 + c8] = qlv;
    const u16* ph = (const u16*)&qhv;
    const u16* pl = (const u16*)&qlv;
    float s = 0.f;
    #pragma unroll
    for (int j = 0; j < 8; ++j) {
      float qv = bf2f(ph[j]) + bf2f(pl[j]);
      s += qv * qv;
    }
    s += __shfl_xor(s, 1);
    s += __shfl_xor(s, 2);
    s += __shfl_xor(s, 4);
    if ((t & 7) == 0) xnorm[row] = 0.5f * s;
  }
  __syncthreads();
  // feature GEMM: wave w owns r-cols [128w, 128w+128)
  f32x4 facc[2][8];
  #pragma unroll
  for (int i = 0; i < 2; ++i)
    #pragma unroll
    for (int j = 0; j < 8; ++j) facc[i][j] = zero4();
  #pragma unroll
  for (int ks = 0; ks < 2; ++ks) {
    bf16x8 ah[2], al[2];
    #pragma unroll
    for (int fm = 0; fm < 2; ++fm) {
      ah[fm] = *(const bf16x8*)&Qh[(fm*16 + lr)*72 + ks*32 + lk];
      al[fm] = *(const bf16x8*)&Ql[(fm*16 + lr)*72 + ks*32 + lk];
    }
    #pragma unroll
    for (int fn = 0; fn < 8; ++fn) {
      int r = w*128 + fn*16 + lr;
      bf16x8 pbh = *(const bf16x8*)&phi[r*HDIM + ks*32 + lk];
      bf16x8 pbl = *(const bf16x8*)&plo[r*HDIM + ks*32 + lk];
      #pragma unroll
      for (int fm = 0; fm < 2; ++fm) {
        facc[fm][fn] = MFMA(al[fm], pbh, facc[fm][fn]);
        facc[fm][fn] = MFMA(ah[fm], pbl, facc[fm][fn]);
        facc[fm][fn] = MFMA(ah[fm], pbh, facc[fm][fn]);
      }
    }
  }
  #pragma unroll
  for (int fm = 0; fm < 2; ++fm)
    #pragma unroll
    for (int fn = 0; fn < 8; ++fn)
      #pragma unroll
      for (int j = 0; j < 4; ++j) {
        int row = fm*16 + l4 + j;
        int r = w*128 + fn*16 + lr;
        float e = __expf(facc[fm][fn][j] - xnorm[row]) * 0.0625f + 1e-6f;
        Qf[row*264 + r] = f2bf(e);
      }
  __syncthreads();
  // PV: out_ext(32x80) = Qf(32x256) @ kv_ext(256x80); wave w owns rows [16w,16w+16)
  f32x4 oacc[5];
  #pragma unroll
  for (int j = 0; j < 5; ++j) oacc[j] = zero4();
  #pragma unroll
  for (int ks = 0; ks < 8; ++ks) {
    bf16x8 a = *(const bf16x8*)&Qf[(w*16 + lr)*264 + ks*32 + lk];
    #pragma unroll
    for (int fn = 0; fn < 5; ++fn) {
      int d = fn*16 + lr;
      bf16x8 bv = *(const bf16x8*)&kvt[((size_t)bh*80 + d)*256 + ks*32 + lk];
      oacc[fn] = MFMA(a, bv, oacc[fn]);
    }
  }
  if (lr == 0) {
    #pragma unroll
    for (int j = 0; j < 4; ++j) denom[w*16 + l4 + j] = oacc[4][j];
  }
  __syncthreads();
  #pragma unroll
  for (int fn = 0; fn < 4; ++fn)
    #pragma unroll
    for (int j = 0; j < 4; ++j) {
      int row = w*16 + l4 + j;
      int d = fn*16 + lr;
      float v = oacc[fn][j] / (denom[row] + 1e-6f);
      attn[((size_t)b * NN + n0 + row) * DD + h * HDIM + d] = f2bf(v);
    }
}

// ---------------- host ----------------

extern "C" void kernel_launch(void* const* d_in, const int* in_sizes, int n_in,
                              void* d_out, int out_size, void* d_ws, size_t ws_size,
                              hipStream_t stream)
{
  const float* x      = (const float*)d_in[0];
  const float* w_qkv  = (const float*)d_in[1];
  const float* w_proj = (const float*)d_in[2];
  const float* b_proj = (const float*)d_in[3];
  const float* proj   = (const float*)d_in[4];
  float* out = (float*)d_out;

  char* p = (char*)d_ws;
  auto alloc = [&](size_t nbytes) {
    char* r = p; p += (nbytes + 255) & ~(size_t)255; return r;
  };
  const size_t NE = (size_t)16777216;  // B*N*D elements
  u16* x2   = (u16*)alloc(NE * 2 * 2);                 // 16384 x 2048 (hi|lo)
  u16* w2qk = (u16*)alloc((size_t)2048 * 2048 * 2);    // duplicated qk weights
  u16* wv   = (u16*)alloc((size_t)1024 * 1024 * 2);
  u16* wpt  = (u16*)alloc((size_t)1024 * 1024 * 2);
  u16* phi  = (u16*)alloc((size_t)16384 * 2);
  u16* plo  = (u16*)alloc((size_t)16384 * 2);
  u16* qhi  = (u16*)alloc(NE * 2);
  u16* qlo  = (u16*)alloc(NE * 2);
  u16* khi  = (u16*)alloc(NE * 2);
  u16* klo  = (u16*)alloc(NE * 2);
  u16* vbuf = (u16*)alloc(NE * 2);
  u16* kvt  = (u16*)alloc((size_t)NBH * 80 * 256 * 2);
  // aliases: x2 dead after v-GEMM (kvpart 42MB <= 64MB); khi dead after k2a (attn 32MB)
  float* kvpart = (float*)x2;
  u16*   attn   = khi;

  split_cast_x2_kernel<<<2048, 256, 0, stream>>>((const float4*)x, x2, (int)(NE / 4));
  split_cast_kernel<<<16, 256, 0, stream>>>(
      (const float4*)proj, (ushort4*)phi, (ushort4*)plo, 16384 / 4);
  transpose_wqkv_kernel<<<dim3(96, 32), 256, 0, stream>>>(w_qkv, w2qk, wv);
  transpose_kernel<<<dim3(32, 32), 256, 0, stream>>>(w_proj, wpt);

  // qk: K-doubled single-product GEMM (x2 @ w2qk^T = xhi*w + xlo*w)
  gemm256_kernel<0><<<dim3(64, 8), 512, 0, stream>>>(
      x2, w2qk, 2048, 2048, 2048, qhi, qlo, khi, klo, nullptr, nullptr);
  // v: hi-only, K=1024 (reads hi half of x2)
  gemm256_kernel<1><<<dim3(64, 4), 512, 0, stream>>>(
      x2, wv, 1024, 2048, 1024, vbuf, nullptr, nullptr, nullptr, nullptr, nullptr);

  k2a_kernel<<<dim3(64, KSP), 256, 0, stream>>>(khi, klo, vbuf, phi, plo, kvpart);
  kv_reduce_kernel<<<dim3(5120), 256, 0, stream>>>(kvpart, kvt);
  k2b_kernel<<<dim3(64, 128), 128, 0, stream>>>(qhi, qlo, kvt, phi, plo, attn);

  gemm256_kernel<2><<<dim3(64, 4), 512, 0, stream>>>(
      attn, wpt, 1024, 1024, 1024,
      nullptr, nullptr, nullptr, nullptr, out, b_proj);
}